// Round 2
// baseline (467.388 us; speedup 1.0000x reference)
//
#include <hip/hip_runtime.h>
#include <math.h>

#define N_TOKENS 32768
#define EMBED    2048
#define NEXP     64
#define TOPK     8
#define BM       64
#define BK       64
#define NCH      (EMBED / BK)     // 32
#define SCS      65
#define THRESH   1e-4f
#define WELEMS   (NEXP * EMBED)
#define FIXGRID  1024

typedef __attribute__((ext_vector_type(8)))  short short8;
typedef __attribute__((ext_vector_type(16))) float f32x16;
typedef __attribute__((ext_vector_type(4)))  unsigned int uint4v;

// one-instruction packed fp32->bf16 RNE (gfx950), D[15:0]=bf16(a), D[31:16]=bf16(b)
__device__ __forceinline__ unsigned pkbf(float a, float b) {
  unsigned r;
  asm("v_cvt_pk_bf16_f32 %0, %1, %2" : "=v"(r) : "v"(a), "v"(b));
  return r;
}

// 8 fp32 -> bf16 hi (RNE) + bf16 lo (RNE of exact residual), packed directly in
// MFMA-operand order.
__device__ __forceinline__ void cvt8(float4 fa, float4 fb, short8* h8, short8* l8) {
  const unsigned h0 = pkbf(fa.x, fa.y), h1 = pkbf(fa.z, fa.w);
  const unsigned h2 = pkbf(fb.x, fb.y), h3 = pkbf(fb.z, fb.w);
  const float l0 = fa.x - __uint_as_float(h0 << 16);
  const float l1 = fa.y - __uint_as_float(h0 & 0xFFFF0000u);
  const float l2 = fa.z - __uint_as_float(h1 << 16);
  const float l3 = fa.w - __uint_as_float(h1 & 0xFFFF0000u);
  const float l4 = fb.x - __uint_as_float(h2 << 16);
  const float l5 = fb.y - __uint_as_float(h2 & 0xFFFF0000u);
  const float l6 = fb.z - __uint_as_float(h3 << 16);
  const float l7 = fb.w - __uint_as_float(h3 & 0xFFFF0000u);
  const uint4v H = {h0, h1, h2, h3};
  const uint4v L = {pkbf(l0, l1), pkbf(l2, l3), pkbf(l4, l5), pkbf(l6, l7)};
  *h8 = __builtin_bit_cast(short8, H);
  *l8 = __builtin_bit_cast(short8, L);
}

// W [64,2048] fp32 -> bf16 hi/lo in MFMA B-fragment layout. Also zeroes gcnt.
__global__ void split_w(const float* __restrict__ W, short* __restrict__ wh,
                        short* __restrict__ wl, int* __restrict__ gcnt) {
  if (blockIdx.x == 0 && threadIdx.x == 0) *gcnt = 0;
  const int T = blockIdx.x * 256 + threadIdx.x;   // 0..16383
  const int n = T >> 8, kg8 = T & 255;
  const float4* W4 = (const float4*)W;
  float4 a = W4[n * 512 + kg8 * 2];
  float4 b = W4[n * 512 + kg8 * 2 + 1];
  short8 h, l;
  cvt8(a, b, &h, &l);
  *(short8*)&wh[(kg8 * 64 + n) * 8] = h;
  *(short8*)&wl[(kg8 * 64 + n) * 8] = l;
}

__global__ __launch_bounds__(256, 2)
void router_kernel(const float* __restrict__ x, const short* __restrict__ wh,
                   const short* __restrict__ wl, const float* __restrict__ bias,
                   int* __restrict__ gcnt, int* __restrict__ glist,
                   float* __restrict__ out) {
  // x staged via global_load_lds, 4 buffers, depth-3 issue / depth-2 steady
  // in-flight. B fragments double-buffered in VGPRs, loaded BEFORE the x
  // prefetch each iter so the compiler's pre-MFMA vmcnt never drains the
  // deep x pipeline (FIFO order: ... B(ch) < x(ch+2) < B(ch+1) < x(ch+3)).
  __shared__ float4 lx[4][1024];     // 64 KB
  float* sc = (float*)&lx[0][0];     // overlay: used only after the K-loop

  const int tid  = threadIdx.x;
  const int t0   = blockIdx.x * BM;
  const int lane = tid & 63;
  const int w    = tid >> 6;
  const int half = lane >> 5;
  const int r5   = lane & 31;
  const int tw   = (w & 1) * 32;
  const int ew   = (w >> 1) * 32;

  const float4* x4g = (const float4*)x;
  const short8* Bh  = (const short8*)wh;
  const short8* Bl  = (const short8*)wl;
  const int boff = half * 64 + ew + r5;

  const int row16 = tid >> 4;
  const int s4    = tid & 15;
  const int c4sw  = s4 ^ row16;
  const int wbase = (tid & 192);

  const float4* gbase = x4g + (size_t)(t0 + row16) * (EMBED / 4) + c4sw;

  const int arow  = tw + r5;
  const int am    = arow & 15;
  const int abase = (arow >> 4) * 256 + am * 16;

  f32x16 acc;
#pragma unroll
  for (int i = 0; i < 16; ++i) acc[i] = 0.f;

  auto ISSUE_X = [&](int ch) {
#pragma unroll
    for (int i = 0; i < 4; ++i)
      __builtin_amdgcn_global_load_lds(
          (const void*)(gbase + (size_t)16 * i * (EMBED / 4) + ch * 16),
          (void*)&lx[ch & 3][i * 256 + wbase], 16, 0, 0);
  };
  auto LOADB = [&](int ch, short8 (&bh)[4], short8 (&bl)[4]) {
#pragma unroll
    for (int s = 0; s < 4; ++s) {
      const int bi = (ch * 4 + s) * 128 + boff;
      bh[s] = Bh[bi]; bl[s] = Bl[bi];
    }
  };
  auto COMPUTE = [&](int ch, short8 (&bh)[4], short8 (&bl)[4]) {
#pragma unroll
    for (int s = 0; s < 4; ++s) {
      const int c0 = s * 4 + half * 2;
      float4 fa = lx[ch & 3][abase + (c0 ^ am)];
      float4 fb = lx[ch & 3][abase + ((c0 + 1) ^ am)];
      short8 ah, al;
      cvt8(fa, fb, &ah, &al);
      acc = __builtin_amdgcn_mfma_f32_32x32x16_bf16(ah, bh[s], acc, 0, 0, 0);
      acc = __builtin_amdgcn_mfma_f32_32x32x16_bf16(ah, bl[s], acc, 0, 0, 0);
      acc = __builtin_amdgcn_mfma_f32_32x32x16_bf16(al, bh[s], acc, 0, 0, 0);
    }
  };

  short8 bh0[4], bl0[4], bh1[4], bl1[4];

  // Prologue FIFO: B0(8), x0(4), x1(4), x2(4). Wait x0 => vmcnt(8).
  LOADB(0, bh0, bl0);
  ISSUE_X(0); ISSUE_X(1); ISSUE_X(2);
  asm volatile("s_waitcnt vmcnt(8)" ::: "memory");

  // Main loop: ch = 0..27, branch-free so compiler waits stay counted.
  for (int t = 0; t < 14; ++t) {
    const int ch = 2 * t;
    // even iter: consume set0/B(ch), load B(ch+1)->set1, issue x(ch+3)
    asm volatile("s_waitcnt vmcnt(24)" ::: "memory");
    __builtin_amdgcn_s_barrier();
    __builtin_amdgcn_sched_barrier(0);
    LOADB(ch + 1, bh1, bl1);
    __builtin_amdgcn_sched_barrier(0);
    ISSUE_X(ch + 3);
    __builtin_amdgcn_sched_barrier(0);
    COMPUTE(ch, bh0, bl0);
    __builtin_amdgcn_sched_barrier(0);
    // odd iter: consume set1/B(ch+1), load B(ch+2)->set0, issue x(ch+4)
    asm volatile("s_waitcnt vmcnt(16)" ::: "memory");
    __builtin_amdgcn_s_barrier();
    __builtin_amdgcn_sched_barrier(0);
    LOADB(ch + 2, bh0, bl0);
    __builtin_amdgcn_sched_barrier(0);
    ISSUE_X(ch + 4);
    __builtin_amdgcn_sched_barrier(0);
    COMPUTE(ch + 1, bh1, bl1);
    __builtin_amdgcn_sched_barrier(0);
  }

  // Epilogue: ch = 28..31 (set0 holds B28 after the loop).
  asm volatile("s_waitcnt vmcnt(24)" ::: "memory");
  __builtin_amdgcn_s_barrier();
  __builtin_amdgcn_sched_barrier(0);
  LOADB(29, bh1, bl1);
  __builtin_amdgcn_sched_barrier(0);
  ISSUE_X(31);
  __builtin_amdgcn_sched_barrier(0);
  COMPUTE(28, bh0, bl0);
  __builtin_amdgcn_sched_barrier(0);

  asm volatile("s_waitcnt vmcnt(16)" ::: "memory");
  __builtin_amdgcn_s_barrier();
  __builtin_amdgcn_sched_barrier(0);
  LOADB(30, bh0, bl0);
  __builtin_amdgcn_sched_barrier(0);
  COMPUTE(29, bh1, bl1);
  __builtin_amdgcn_sched_barrier(0);

  __builtin_amdgcn_s_barrier();
  __builtin_amdgcn_sched_barrier(0);
  LOADB(31, bh1, bl1);
  __builtin_amdgcn_sched_barrier(0);
  COMPUTE(30, bh0, bl0);
  __builtin_amdgcn_sched_barrier(0);

  __builtin_amdgcn_s_barrier();
  __builtin_amdgcn_sched_barrier(0);
  COMPUTE(31, bh1, bl1);

  __syncthreads();

  // C layout (32x32): col = lane&31, row = (reg&3) + 8*(reg>>2) + 4*(lane>>5)
#pragma unroll
  for (int reg = 0; reg < 16; ++reg) {
    const int row = (reg & 3) + 8 * (reg >> 2) + 4 * half;
    sc[(tw + row) * SCS + ew + r5] = acc[reg];
  }
  __syncthreads();

  float* rout = out;
  float* iout = out + (size_t)N_TOKENS * NEXP;
  const float bias_l = bias[lane];

  for (int tb = 0; tb < 4; ++tb) {
    const int tbase = w * 16 + tb * 4;
    float orig[4]; unsigned cur[4];
#pragma unroll
    for (int i = 0; i < 4; ++i) {
      orig[i] = sc[(tbase + i) * SCS + lane] + bias_l;
      unsigned b = __float_as_uint(orig[i]);
      unsigned u = b ^ (((unsigned)((int)b >> 31)) | 0x80000000u);
      cur[i] = (u & 0xFFFFFFC0u) | (63u - (unsigned)lane);
    }
    float m[4], Z[4], ming[4], prev[4], morig[4];
    int myidx[4];
#pragma unroll
    for (int i = 0; i < 4; ++i) { morig[i] = 0.f; myidx[i] = 0; ming[i] = 1e30f; }

#pragma unroll
    for (int r = 0; r < 9; ++r) {
      unsigned v[4];
#pragma unroll
      for (int i = 0; i < 4; ++i) v[i] = cur[i];
#pragma unroll
      for (int s2 = 1; s2 < 64; s2 <<= 1) {
#pragma unroll
        for (int i = 0; i < 4; ++i) {
          unsigned o = (unsigned)__shfl_xor((int)v[i], s2);
          v[i] = v[i] > o ? v[i] : o;
        }
      }
#pragma unroll
      for (int i = 0; i < 4; ++i) {
        unsigned vb = (v[i] & 0x80000000u) ? (v[i] ^ 0x80000000u) : ~v[i];
        float fv = __uint_as_float(vb);
        if (r == 0) { m[i] = fmaxf(fv, 0.f); Z[i] = 56.f * expf(-m[i]) + expf(fv - m[i]); }
        else {
          ming[i] = fminf(ming[i], prev[i] - fv);
          if (r < 8) Z[i] += expf(fv - m[i]);
        }
        prev[i] = fv;
        if (r < 8) {
          if (lane == r) myidx[i] = 63 - (int)(v[i] & 63u);
          if (cur[i] == v[i]) { morig[i] = orig[i]; cur[i] = 0u; }
        }
      }
    }
#pragma unroll
    for (int i = 0; i < 4; ++i) {
      const int t = tbase + i;
      if (ming[i] < THRESH) {
        if (lane == 0) { int p = atomicAdd(gcnt, 1); glist[p] = t0 + t; }
      } else {
        const float p = expf(morig[i] - m[i]) / Z[i];
        rout[(size_t)(t0 + t) * NEXP + lane] = p;
        if (lane < TOPK) iout[(size_t)(t0 + t) * TOPK + lane] = (float)myidx[i];
      }
    }
  }
}

// Exact fp64 recompute for ambiguous tokens; one token per block-iteration.
__global__ __launch_bounds__(256, 4)
void fixup_kernel(const float* __restrict__ x, const float* __restrict__ Wf,
                  const float* __restrict__ bias, const int* __restrict__ gcnt,
                  const int* __restrict__ glist, float* __restrict__ out) {
  __shared__ float4 xsh[512];        // 8 KB x row
  __shared__ double sco[NEXP];
  const int tid  = threadIdx.x;
  const int lane = tid & 63;
  const int w    = tid >> 6;
  float* rout = out;
  float* iout = out + (size_t)N_TOKENS * NEXP;
  const int cnt = *gcnt;

  for (int j = blockIdx.x; j < cnt; j += FIXGRID) {
    const int tok = glist[j];
    const float4* xr = (const float4*)x + (size_t)tok * 512;
    xsh[tid] = xr[tid];
    xsh[tid + 256] = xr[tid + 256];
    __syncthreads();

    // wave w handles experts 16w..16w+15, lanes fully coalesced over k
    for (int i = 0; i < 16; ++i) {
      const int e = w * 16 + i;
      const float4* wr = (const float4*)Wf + (size_t)e * 512;
      double a = 0.0;
#pragma unroll
      for (int q = 0; q < 8; ++q) {
        float4 wv = wr[q * 64 + lane];     // contiguous 1 KB per instruction
        float4 xv = xsh[q * 64 + lane];
        a = fma((double)xv.x, (double)wv.x, a);
        a = fma((double)xv.y, (double)wv.y, a);
        a = fma((double)xv.z, (double)wv.z, a);
        a = fma((double)xv.w, (double)wv.w, a);
      }
#pragma unroll
      for (int s2 = 1; s2 < 64; s2 <<= 1) a += __shfl_xor(a, s2);
      if (lane == 0) sco[e] = a + (double)bias[e];
    }
    __syncthreads();

    if (w == 0) {                      // exact fp64 top-8
      const double orig = sco[lane];
      double curd = orig, vals[8];
      int myidx = 0; double mym = 0.0;
#pragma unroll
      for (int r = 0; r < 8; ++r) {
        double v = curd; int id = lane;
#pragma unroll
        for (int s2 = 1; s2 < 64; s2 <<= 1) {
          const double ov = __shfl_xor(v, s2);
          const int    oi = __shfl_xor(id, s2);
          if (ov > v || (ov == v && oi < id)) { v = ov; id = oi; }
        }
        vals[r] = v;
        if (lane == r)  myidx = id;
        if (lane == id) { mym = orig; curd = -1e300; }
      }
      const double md = fmax(vals[0], 0.0);
      double Zd = 56.0 * exp(-md);
#pragma unroll
      for (int r = 0; r < 8; ++r) Zd += exp(vals[r] - md);
      const double p = exp(mym - md) / Zd;
      rout[(size_t)tok * NEXP + lane] = (float)p;
      if (lane < TOPK) iout[(size_t)tok * TOPK + lane] = (float)myidx;
    }
    __syncthreads();
  }
}

extern "C" void kernel_launch(void* const* d_in, const int* in_sizes, int n_in,
                              void* d_out, int out_size, void* d_ws, size_t ws_size,
                              hipStream_t stream) {
  const float* x = (const float*)d_in[0];
  const float* W = (const float*)d_in[1];
  const float* b = (const float*)d_in[2];
  short* wh = (short*)d_ws;
  short* wl = wh + WELEMS;
  int* gcnt  = (int*)(wl + WELEMS);      // 1 MB offset, 4-aligned
  int* glist = gcnt + 4;                 // capacity 32768 ints

  split_w<<<64, 256, 0, stream>>>(W, wh, wl, gcnt);
  router_kernel<<<N_TOKENS / BM, 256, 0, stream>>>(x, wh, wl, b, gcnt, glist,
                                                   (float*)d_out);
  fixup_kernel<<<FIXGRID, 256, 0, stream>>>(x, W, b, gcnt, glist, (float*)d_out);
}